// Round 1
// baseline (174.354 us; speedup 1.0000x reference)
//
#include <hip/hip_runtime.h>

// Problem constants (fixed by the reference's setup_inputs)
constexpr int B = 32;
constexpr int L = 256;
constexpr int H = 512;
constexpr int HV = H / 4;  // float4 elements per row = 128

// Kernel 1: per-batch inclusive cumsum of durations. 32 blocks x 256 threads.
__global__ void duration_scan_kernel(const int* __restrict__ dur,
                                     int* __restrict__ csum) {
    __shared__ int s[L];
    const int b = blockIdx.x;
    const int i = threadIdx.x;
    s[i] = dur[b * L + i];
    __syncthreads();
    // Hillis-Steele inclusive scan over 256 elements (8 steps)
    #pragma unroll
    for (int off = 1; off < L; off <<= 1) {
        int t = (i >= off) ? s[i - off] : 0;
        __syncthreads();
        s[i] += t;
        __syncthreads();
    }
    csum[b * L + i] = s[i];
}

// Kernel 2: expansion. grid = (T, B), block = 128 threads.
// Each block produces one output row out[b, t, :] (512 floats = 128 float4)
// and the mask element mask[b, t].
__global__ void expand_kernel(const float4* __restrict__ x,
                              const int* __restrict__ csum,
                              float4* __restrict__ out,
                              float* __restrict__ mask,
                              int T) {
    __shared__ int sc[L];
    const int b = blockIdx.y;
    const int t = blockIdx.x;
    const int tid = threadIdx.x;  // 0..127

    // Stage this batch's csum row into LDS (2 ints/thread)
    sc[tid] = csum[b * L + tid];
    sc[tid + 128] = csum[b * L + tid + 128];
    __syncthreads();

    const int total = sc[L - 1];

    // searchsorted(csum, t, side='right'): first index with sc[idx] > t.
    // Uniform across the block -> LDS broadcast reads, no divergence.
    int lo = 0, hi = L;
    while (lo < hi) {
        int mid = (lo + hi) >> 1;
        if (sc[mid] <= t) lo = mid + 1; else hi = mid;
    }
    const int idx = (lo < L - 1) ? lo : (L - 1);

    float4 val;
    if (t < total) {
        val = x[((size_t)(b * L + idx)) * HV + tid];
    } else {
        val = make_float4(0.f, 0.f, 0.f, 0.f);
    }
    out[((size_t)b * T + t) * HV + tid] = val;

    if (tid == 0) {
        mask[(size_t)b * T + t] = (t < total) ? 1.0f : 0.0f;
    }
}

extern "C" void kernel_launch(void* const* d_in, const int* in_sizes, int n_in,
                              void* d_out, int out_size, void* d_ws, size_t ws_size,
                              hipStream_t stream) {
    const float* x = (const float*)d_in[0];       // (B, L, H) fp32
    const int* dur = (const int*)d_in[1];         // (B, L) int32
    float* out = (float*)d_out;

    // out_size = B*T*H + B*T = B*T*(H+1)  ->  T
    const int T = out_size / (B * (H + 1));

    int* csum = (int*)d_ws;  // B*L ints = 32 KB, well within ws_size

    duration_scan_kernel<<<B, L, 0, stream>>>(dur, csum);

    float* mask_out = out + (size_t)B * T * H;
    dim3 grid(T, B);
    expand_kernel<<<grid, 128, 0, stream>>>((const float4*)x, csum,
                                            (float4*)out, mask_out, T);
}

// Round 2
// 154.758 us; speedup vs baseline: 1.1266x; 1.1266x over previous
//
#include <hip/hip_runtime.h>

// Problem constants (fixed by the reference's setup_inputs)
constexpr int B = 32;
constexpr int L = 256;
constexpr int H = 512;
constexpr int HV = H / 4;   // 128 float4 per row
constexpr int CHUNK = 16;   // output t-rows per block

// Fused kernel: per-block cumsum recompute (cheap: 256 ints, 8 scan steps)
// + chunked expansion. grid = (ceil(T/CHUNK), B), block = 256 threads.
// Each block writes out[b, t0:t0+CHUNK, :] (32 KB contiguous) + 16 mask floats.
__global__ __launch_bounds__(256) void lr_fused_kernel(
    const float4* __restrict__ x,   // (B, L, HV) float4
    const int* __restrict__ dur,    // (B, L)
    float4* __restrict__ out,       // (B, T, HV) float4
    float* __restrict__ mask,       // (B, T)
    int T) {
    __shared__ int sc[L];
    const int b = blockIdx.y;
    const int tid = threadIdx.x;    // 0..255

    // --- inclusive scan of durations for batch b (Hillis-Steele, 8 steps) ---
    sc[tid] = dur[b * L + tid];
    __syncthreads();
    #pragma unroll
    for (int off = 1; off < L; off <<= 1) {
        int t = (tid >= off) ? sc[tid - off] : 0;
        __syncthreads();
        sc[tid] += t;
        __syncthreads();
    }
    const int total = sc[L - 1];

    // --- expansion: two t-rows per iteration (halves of the block) ---
    const int t0 = blockIdx.x * CHUNK;
    const int half = tid >> 7;      // 0 or 1
    const int lane = tid & 127;     // float4 lane within the row

    // searchsorted(csum, t, 'right') for this half's first t: first idx with
    // sc[idx] > t. Uniform within each half -> LDS broadcast, no divergence.
    const int tfirst = t0 + half;
    int lo = 0, hi = L;
    while (lo < hi) {
        int mid = (lo + hi) >> 1;
        if (sc[mid] <= tfirst) lo = mid + 1; else hi = mid;
    }
    int idx = lo;   // in [0, L]

    #pragma unroll
    for (int i = 0; i < CHUNK / 2; ++i) {
        const int t = t0 + 2 * i + half;
        // monotone advance (t increases by 2 per iter; ~2 total advances/chunk)
        while (idx < L && sc[idx] <= t) ++idx;
        const int gidx = (idx < L - 1) ? idx : (L - 1);  // clip to L-1
        if (t < T) {
            float4 val = make_float4(0.f, 0.f, 0.f, 0.f);
            if (t < total) {
                val = x[((size_t)(b * L + gidx)) * HV + lane];
            }
            out[((size_t)b * T + t) * HV + lane] = val;
        }
    }

    // --- mask: 16 consecutive floats per block, coalesced ---
    if (tid < CHUNK) {
        const int t = t0 + tid;
        if (t < T) {
            mask[(size_t)b * T + t] = (t < total) ? 1.0f : 0.0f;
        }
    }
}

extern "C" void kernel_launch(void* const* d_in, const int* in_sizes, int n_in,
                              void* d_out, int out_size, void* d_ws, size_t ws_size,
                              hipStream_t stream) {
    const float* x = (const float*)d_in[0];       // (B, L, H) fp32
    const int* dur = (const int*)d_in[1];         // (B, L) int32
    float* out = (float*)d_out;

    // out_size = B*T*H + B*T = B*T*(H+1)  ->  T
    const int T = out_size / (B * (H + 1));

    float* mask_out = out + (size_t)B * T * H;
    dim3 grid((T + CHUNK - 1) / CHUNK, B);
    lr_fused_kernel<<<grid, 256, 0, stream>>>((const float4*)x, dur,
                                              (float4*)out, mask_out, T);
}